// Round 1
// baseline (372.466 us; speedup 1.0000x reference)
//
#include <hip/hip_runtime.h>
#include <math.h>

#define NN 50000
#define EE 800000
#define HH 4
#define CC 64
#define DE 16
#define GG 64
#define HC 256          // H*C
#define NEG 0.2f
#define EPSV 1e-5f
#define NB 196          // scan blocks: 196*256 = 50176 >= NN

typedef __attribute__((ext_vector_type(8))) short short8;
typedef __attribute__((ext_vector_type(4))) float f32x4;

__device__ __forceinline__ unsigned short f2bf(float f) {
  unsigned int x = __float_as_uint(f);
  unsigned int r = (x + 0x7fff + ((x >> 16) & 1)) >> 16;  // round-nearest-even
  return (unsigned short)r;
}
__device__ __forceinline__ float lrelu(float a) {
  return fmaxf(a, 0.f) + NEG * fminf(a, 0.f);
}

// K0: blocks 0..63 (b = k index): Wbt[t][k] = bf16(W[k][colmap(t)]),
//     colmap(t)=(t&3)*64+(t>>2) (so x16 = node @ Wb lands in [n][c][h] order).
//     Transposed layout: B fragment for MFMA is one contiguous ushort8.
//     block 64: v_edge[d][h] = sum_c We[d][h*C+c]*att_edge[h][c].
__global__ __launch_bounds__(256) void k_prep(
    const float* __restrict__ W, const float* __restrict__ We,
    const float* __restrict__ ae_, unsigned short* __restrict__ Wbt,
    float* __restrict__ v_edge) {
  int b = blockIdx.x, t = threadIdx.x;
  if (b < 64) {
    Wbt[(size_t)t * 64 + b] = f2bf(W[b * HC + (t & 3) * 64 + (t >> 2)]);
  } else if (t < DE * HH) {
    int d = t >> 2, h = t & 3;
    float s = 0.f;
    for (int c = 0; c < CC; ++c) s += We[d * HC + h * CC + c] * ae_[h * CC + c];
    v_edge[t] = s;
  }
}

// K1: MFMA projection. One block = 16 rows x 256 cols (4 waves x 4 col-tiles,
// 2 MFMAs each, K=64). Fused per-node logits a_src/a_dst from the fp32
// accumulator (shfl_xor + small LDS reduce). Verified gfx950 layouts:
// A[m=lane&15][k=quad*8+j], B[k=quad*8+j][n=lane&15], C col=lane&15,row=quad*4+r.
// B fragments now load as two 16B ushort8 from the transposed Wbt.
__global__ __launch_bounds__(256) void k_xproj(
    const float* __restrict__ node, const unsigned short* __restrict__ Wbt,
    const float* __restrict__ att_src, const float* __restrict__ att_dst,
    unsigned short* __restrict__ x16, float* __restrict__ a_src,
    float* __restrict__ a_dst) {
  int lane = threadIdx.x & 63;
  int w = threadIdx.x >> 6;
  int m = lane & 15, quad = lane >> 4;
  int m0 = blockIdx.x * 16;
  const float* arow = node + (size_t)(m0 + m) * CC + quad * 8;
  float4 af0 = *(const float4*)(arow);
  float4 af1 = *(const float4*)(arow + 4);
  float4 af2 = *(const float4*)(arow + 32);
  float4 af3 = *(const float4*)(arow + 36);
  short8 a0 = {(short)f2bf(af0.x), (short)f2bf(af0.y), (short)f2bf(af0.z),
               (short)f2bf(af0.w), (short)f2bf(af1.x), (short)f2bf(af1.y),
               (short)f2bf(af1.z), (short)f2bf(af1.w)};
  short8 a1 = {(short)f2bf(af2.x), (short)f2bf(af2.y), (short)f2bf(af2.z),
               (short)f2bf(af2.w), (short)f2bf(af3.x), (short)f2bf(af3.y),
               (short)f2bf(af3.z), (short)f2bf(af3.w)};
  float sa[4] = {0, 0, 0, 0}, sd[4] = {0, 0, 0, 0};
#pragma unroll
  for (int i = 0; i < 4; ++i) {
    int t = (w * 4 + i) * 16 + m;
    const unsigned short* bp = Wbt + (size_t)t * 64 + quad * 8;
    short8 b0 = *(const short8*)(bp);
    short8 b1 = *(const short8*)(bp + 32);
    f32x4 acc = {0.f, 0.f, 0.f, 0.f};
    acc = __builtin_amdgcn_mfma_f32_16x16x32_bf16(a0, b0, acc, 0, 0, 0);
    acc = __builtin_amdgcn_mfma_f32_16x16x32_bf16(a1, b1, acc, 0, 0, 0);
    float us_t = att_src[(t & 3) * CC + (t >> 2)];
    float ud_t = att_dst[(t & 3) * CC + (t >> 2)];
#pragma unroll
    for (int r = 0; r < 4; ++r) {
      x16[(size_t)(m0 + quad * 4 + r) * HC + t] = f2bf(acc[r]);
      sa[r] += acc[r] * us_t;
      sd[r] += acc[r] * ud_t;
    }
  }
  __shared__ float lss[4][16][4], lsd[4][16][4];
#pragma unroll
  for (int r = 0; r < 4; ++r) {
    sa[r] += __shfl_xor(sa[r], 4);
    sa[r] += __shfl_xor(sa[r], 8);
    sd[r] += __shfl_xor(sd[r], 4);
    sd[r] += __shfl_xor(sd[r], 8);
  }
  if ((lane & 12) == 0) {
#pragma unroll
    for (int r = 0; r < 4; ++r) {
      lss[w][quad * 4 + r][lane & 3] = sa[r];
      lsd[w][quad * 4 + r][lane & 3] = sd[r];
    }
  }
  __syncthreads();
  int t = threadIdx.x;
  if (t < 64) {
    int row = t >> 2, h = t & 3;
    a_src[(size_t)(m0 + row) * 4 + h] =
        lss[0][row][h] + lss[1][row][h] + lss[2][row][h] + lss[3][row][h];
    a_dst[(size_t)(m0 + row) * 4 + h] =
        lsd[0][row][h] + lsd[1][row][h] + lsd[2][row][h] + lsd[3][row][h];
  }
}

// K2: dst histogram.
__global__ __launch_bounds__(256) void k_hist(
    const int* __restrict__ ei, int* __restrict__ hist) {
  int e = blockIdx.x * 256 + threadIdx.x;
  if (e >= EE) return;
  atomicAdd(&hist[ei[EE + e]], 1);
}

// K3a: coalesced per-block sums of the histogram.
__global__ __launch_bounds__(256) void k_scanA(
    const int* __restrict__ hist, int* __restrict__ bsum) {
  __shared__ int s[256];
  int t = threadIdx.x;
  int idx = blockIdx.x * 256 + t;
  s[t] = (idx < NN) ? hist[idx] : 0;
  __syncthreads();
  for (int d = 128; d; d >>= 1) {
    if (t < d) s[t] += s[t + d];
    __syncthreads();
  }
  if (t == 0) bsum[blockIdx.x] = s[0];
}

// K3b: single block: exclusive scan of NB block sums.
__global__ __launch_bounds__(256) void k_scanB(
    const int* __restrict__ bsum, int* __restrict__ boff,
    int* __restrict__ ptr) {
  __shared__ int s[256];
  int t = threadIdx.x;
  int v = (t < NB) ? bsum[t] : 0;
  s[t] = v;
  __syncthreads();
  for (int d = 1; d < 256; d <<= 1) {
    int u = (t >= d) ? s[t - d] : 0;
    __syncthreads();
    s[t] += u;
    __syncthreads();
  }
  if (t < NB) boff[t] = s[t] - v;
  if (t == 255) ptr[NN] = s[255];
}

// K3c: per-block exclusive scan + block offset -> ptr, cursor.
__global__ __launch_bounds__(256) void k_scanC(
    const int* __restrict__ hist, const int* __restrict__ boff,
    int* __restrict__ ptr, int* __restrict__ cursor) {
  __shared__ int s[256];
  int t = threadIdx.x;
  int idx = blockIdx.x * 256 + t;
  int v = (idx < NN) ? hist[idx] : 0;
  s[t] = v;
  __syncthreads();
  for (int d = 1; d < 256; d <<= 1) {
    int u = (t >= d) ? s[t - d] : 0;
    __syncthreads();
    s[t] += u;
    __syncthreads();
  }
  if (idx < NN) {
    int p = boff[blockIdx.x] + s[t] - v;
    ptr[idx] = p;
    cursor[idx] = p;
  }
}

// K4: fused edge pass: t = exp(lrelu(a_src[sn]+a_dst[dn]+edge_attr@v)), then
// scatter ONE packed uint4 {bf16 t0..t3, sn, e} into the dst-sorted slot.
// Also writes t_lin[e] (coalesced) so the att output can be produced by a
// coalesced kernel instead of a scattered write from k_gat.
__global__ __launch_bounds__(256) void k_edge_perm(
    const float* __restrict__ edge_attr, const int* __restrict__ ei,
    const float* __restrict__ a_src, const float* __restrict__ a_dst,
    const float* __restrict__ v_edge, int* __restrict__ cursor,
    uint4* __restrict__ recs, uint2* __restrict__ t_lin) {
  __shared__ float vs[DE * HH];
  int t = threadIdx.x;
  if (t < DE * HH) vs[t] = v_edge[t];
  __syncthreads();
  int e = blockIdx.x * 256 + t;
  if (e >= EE) return;
  const float4* ea4 = (const float4*)(edge_attr + (size_t)e * DE);
  float ae[4] = {0, 0, 0, 0};
#pragma unroll
  for (int dd = 0; dd < 4; ++dd) {
    float4 ev = ea4[dd];
    float evs[4] = {ev.x, ev.y, ev.z, ev.w};
#pragma unroll
    for (int j = 0; j < 4; ++j) {
      int d = dd * 4 + j;
#pragma unroll
      for (int h = 0; h < 4; ++h) ae[h] += evs[j] * vs[d * 4 + h];
    }
  }
  int sn = ei[e], dn = ei[EE + e];
  float4 as4 = *(const float4*)(a_src + (size_t)sn * 4);
  float4 ad4 = *(const float4*)(a_dst + (size_t)dn * 4);
  float t0 = __expf(lrelu(as4.x + ad4.x + ae[0]));
  float t1 = __expf(lrelu(as4.y + ad4.y + ae[1]));
  float t2 = __expf(lrelu(as4.z + ad4.z + ae[2]));
  float t3 = __expf(lrelu(as4.w + ad4.w + ae[3]));
  uint4 rec;
  rec.x = (unsigned int)f2bf(t0) | ((unsigned int)f2bf(t1) << 16);
  rec.y = (unsigned int)f2bf(t2) | ((unsigned int)f2bf(t3) << 16);
  rec.z = (unsigned int)sn;
  rec.w = (unsigned int)e;
  uint2 tl;
  tl.x = rec.x;
  tl.y = rec.y;
  t_lin[e] = tl;
  int pos = atomicAdd(&cursor[dn], 1);
  recs[pos] = rec;
}

// K5: one wave per dst node. Batched 4 edges/iteration: 4 independent 16B rec
// loads then 4 independent 512B row gathers in flight (x2 via unroll) to cover
// L2/HBM gather latency. Emits out_acc + per-node 1/denom (rinv); att output
// moved to coalesced k_att.
__global__ __launch_bounds__(256) void k_gat(
    const int* __restrict__ ptr, const uint4* __restrict__ recs,
    const unsigned short* __restrict__ x16, float* __restrict__ out_acc,
    float* __restrict__ rinv) {
  int lane = threadIdx.x & 63;
  int w = threadIdx.x >> 6;
  int v = blockIdx.x * 4 + w;
  int start = ptr[v], end = ptr[v + 1];
  float d0 = 0.f, d1 = 0.f, d2 = 0.f, d3 = 0.f;
  float acc0 = 0.f, acc1 = 0.f, acc2 = 0.f, acc3 = 0.f;
  const unsigned short* xb = x16 + lane * 4;
  int j = start;
#pragma unroll 2
  for (; j + 4 <= end; j += 4) {
    uint4 r0 = recs[j];
    uint4 r1 = recs[j + 1];
    uint4 r2 = recs[j + 2];
    uint4 r3 = recs[j + 3];
    uint2 u0 = *(const uint2*)(xb + (size_t)r0.z * HC);
    uint2 u1 = *(const uint2*)(xb + (size_t)r1.z * HC);
    uint2 u2 = *(const uint2*)(xb + (size_t)r2.z * HC);
    uint2 u3 = *(const uint2*)(xb + (size_t)r3.z * HC);
    {
      float t0 = __uint_as_float(r0.x << 16);
      float t1 = __uint_as_float(r0.x & 0xffff0000u);
      float t2 = __uint_as_float(r0.y << 16);
      float t3 = __uint_as_float(r0.y & 0xffff0000u);
      d0 += t0; d1 += t1; d2 += t2; d3 += t3;
      acc0 += t0 * __uint_as_float(u0.x << 16);
      acc1 += t1 * __uint_as_float(u0.x & 0xffff0000u);
      acc2 += t2 * __uint_as_float(u0.y << 16);
      acc3 += t3 * __uint_as_float(u0.y & 0xffff0000u);
    }
    {
      float t0 = __uint_as_float(r1.x << 16);
      float t1 = __uint_as_float(r1.x & 0xffff0000u);
      float t2 = __uint_as_float(r1.y << 16);
      float t3 = __uint_as_float(r1.y & 0xffff0000u);
      d0 += t0; d1 += t1; d2 += t2; d3 += t3;
      acc0 += t0 * __uint_as_float(u1.x << 16);
      acc1 += t1 * __uint_as_float(u1.x & 0xffff0000u);
      acc2 += t2 * __uint_as_float(u1.y << 16);
      acc3 += t3 * __uint_as_float(u1.y & 0xffff0000u);
    }
    {
      float t0 = __uint_as_float(r2.x << 16);
      float t1 = __uint_as_float(r2.x & 0xffff0000u);
      float t2 = __uint_as_float(r2.y << 16);
      float t3 = __uint_as_float(r2.y & 0xffff0000u);
      d0 += t0; d1 += t1; d2 += t2; d3 += t3;
      acc0 += t0 * __uint_as_float(u2.x << 16);
      acc1 += t1 * __uint_as_float(u2.x & 0xffff0000u);
      acc2 += t2 * __uint_as_float(u2.y << 16);
      acc3 += t3 * __uint_as_float(u2.y & 0xffff0000u);
    }
    {
      float t0 = __uint_as_float(r3.x << 16);
      float t1 = __uint_as_float(r3.x & 0xffff0000u);
      float t2 = __uint_as_float(r3.y << 16);
      float t3 = __uint_as_float(r3.y & 0xffff0000u);
      d0 += t0; d1 += t1; d2 += t2; d3 += t3;
      acc0 += t0 * __uint_as_float(u3.x << 16);
      acc1 += t1 * __uint_as_float(u3.x & 0xffff0000u);
      acc2 += t2 * __uint_as_float(u3.y << 16);
      acc3 += t3 * __uint_as_float(u3.y & 0xffff0000u);
    }
  }
  for (; j < end; ++j) {
    uint4 rec = recs[j];
    float t0 = __uint_as_float(rec.x << 16);
    float t1 = __uint_as_float(rec.x & 0xffff0000u);
    float t2 = __uint_as_float(rec.y << 16);
    float t3 = __uint_as_float(rec.y & 0xffff0000u);
    uint2 u = *(const uint2*)(xb + (size_t)rec.z * HC);
    d0 += t0; d1 += t1; d2 += t2; d3 += t3;
    acc0 += t0 * __uint_as_float(u.x << 16);
    acc1 += t1 * __uint_as_float(u.x & 0xffff0000u);
    acc2 += t2 * __uint_as_float(u.y << 16);
    acc3 += t3 * __uint_as_float(u.y & 0xffff0000u);
  }
  float r0 = 1.f / (d0 + 1e-16f), r1 = 1.f / (d1 + 1e-16f);
  float r2 = 1.f / (d2 + 1e-16f), r3 = 1.f / (d3 + 1e-16f);
  out_acc[(size_t)v * CC + lane] =
      0.25f * (r0 * acc0 + r1 * acc1 + r2 * acc2 + r3 * acc3);
  if (lane == 0)
    *(float4*)(rinv + (size_t)v * 4) = make_float4(r0, r1, r2, r3);
}

// K5b: coalesced att output: att[e] = bf16(t[e]) * rinv[dst[e]].
// Same numerics as the old scattered write (identical bf16 t, identical denom).
__global__ __launch_bounds__(256) void k_att(
    const int* __restrict__ ei, const uint2* __restrict__ t_lin,
    const float* __restrict__ rinv, float* __restrict__ att_out) {
  int e = blockIdx.x * 256 + threadIdx.x;
  if (e >= EE) return;
  uint2 tl = t_lin[e];
  int dn = ei[EE + e];
  float4 r = *(const float4*)(rinv + (size_t)dn * 4);
  float t0 = __uint_as_float(tl.x << 16);
  float t1 = __uint_as_float(tl.x & 0xffff0000u);
  float t2 = __uint_as_float(tl.y << 16);
  float t3 = __uint_as_float(tl.y & 0xffff0000u);
  *(float4*)(att_out + (size_t)e * 4) =
      make_float4(t0 * r.x, t1 * r.y, t2 * r.z, t3 * r.w);
}

// K6: GraphNorm stats, one block per group (batch sorted -> contiguous runs).
__global__ __launch_bounds__(256) void k_stats(
    const int* __restrict__ batch, const float* __restrict__ out_acc,
    const float* __restrict__ bias, const float* __restrict__ gns,
    float* __restrict__ mean_s, float* __restrict__ istd) {
  int g = blockIdx.x;
  int lane = threadIdx.x & 63;
  int w = threadIdx.x >> 6;
  int lo = 0, hi = NN;
  while (lo < hi) {
    int mid = (lo + hi) >> 1;
    if (batch[mid] < g) lo = mid + 1; else hi = mid;
  }
  int start = lo;
  hi = NN;
  while (lo < hi) {
    int mid = (lo + hi) >> 1;
    if (batch[mid] < g + 1) lo = mid + 1; else hi = mid;
  }
  int end = lo;
  float b = bias[lane];
  float s1 = 0.f, s2 = 0.f;
  for (int n = start + w; n < end; n += 4) {
    float v = out_acc[(size_t)n * CC + lane] + b;
    s1 += v;
    s2 += v * v;
  }
  __shared__ float l1[4][64], l2[4][64];
  l1[w][lane] = s1;
  l2[w][lane] = s2;
  __syncthreads();
  if (w == 0) {
    s1 = l1[0][lane] + l1[1][lane] + l1[2][lane] + l1[3][lane];
    s2 = l2[0][lane] + l2[1][lane] + l2[2][lane] + l2[3][lane];
    float c = fmaxf((float)(end - start), 1.0f);
    float mean = s1 / c;
    float ms = mean * gns[lane];
    float var = s2 / c - 2.f * ms * mean + ms * ms;
    mean_s[g * CC + lane] = ms;
    istd[g * CC + lane] = rsqrtf(var + EPSV);
  }
}

// K7: normalize + affine + relu -> y
__global__ __launch_bounds__(256) void k_final(
    const int* __restrict__ batch, const float* __restrict__ out_acc,
    const float* __restrict__ bias, const float* __restrict__ mean_s,
    const float* __restrict__ istd, const float* __restrict__ gnw,
    const float* __restrict__ gnb, float* __restrict__ y) {
  int lane = threadIdx.x & 63;
  int n = blockIdx.x * 4 + (threadIdx.x >> 6);
  int g = batch[n];
  float v = out_acc[(size_t)n * CC + lane] + bias[lane];
  float o = (v - mean_s[g * CC + lane]) * istd[g * CC + lane];
  float r = gnw[lane] * o + gnb[lane];
  y[(size_t)n * CC + lane] = fmaxf(r, 0.0f);
}

extern "C" void kernel_launch(void* const* d_in, const int* in_sizes, int n_in,
                              void* d_out, int out_size, void* d_ws, size_t ws_size,
                              hipStream_t stream) {
  const float* node = (const float*)d_in[0];
  const int* ei = (const int*)d_in[1];
  const float* eatt = (const float*)d_in[2];
  const int* batch = (const int*)d_in[3];
  const float* W = (const float*)d_in[4];
  const float* We = (const float*)d_in[5];
  const float* att_src = (const float*)d_in[6];
  const float* att_dst = (const float*)d_in[7];
  const float* att_edge = (const float*)d_in[8];
  const float* bias = (const float*)d_in[9];
  const float* gnw = (const float*)d_in[10];
  const float* gnb = (const float*)d_in[11];
  const float* gns = (const float*)d_in[12];

  float* ws = (float*)d_ws;
  size_t off = 0;
  uint4* recs = (uint4*)(ws + off);  off += (size_t)EE * 4;  // 12.8 MB
  float* a_src = ws + off;    off += (size_t)NN * HH;
  float* a_dst = ws + off;    off += (size_t)NN * HH;
  float* v_edge = ws + off;   off += 64;
  float* mean_s = ws + off;   off += GG * CC;
  float* istd = ws + off;     off += GG * CC;
  float* out_acc = ws + off;  off += (size_t)NN * CC;
  float* rinv = ws + off;     off += (size_t)NN * HH;     // 0.8 MB
  uint2* t_lin = (uint2*)(ws + off);
  off += (size_t)EE * 2;                                  // 6.4 MB
  unsigned short* x16 = (unsigned short*)(ws + off);
  off += (size_t)NN * HC / 2;                             // 12.8M ushort
  unsigned short* Wbt = (unsigned short*)(ws + off);
  off += (size_t)CC * HC / 2;                             // 16K ushort
  int* iws = (int*)(ws + off);
  size_t ioff = 0;
  int* hist = iws + ioff;     ioff += NN;
  int* ptr = iws + ioff;      ioff += NN + 1;
  int* cursor = iws + ioff;   ioff += NN;
  int* bsum = iws + ioff;     ioff += NB;
  int* boff = iws + ioff;     ioff += NB;

  hipMemsetAsync(hist, 0, NN * sizeof(int), stream);

  float* y_out = (float*)d_out;
  float* att_out = (float*)d_out + (size_t)NN * CC;

  k_prep<<<65, 256, 0, stream>>>(W, We, att_edge, Wbt, v_edge);
  k_hist<<<(EE + 255) / 256, 256, 0, stream>>>(ei, hist);
  k_xproj<<<NN / 16, 256, 0, stream>>>(node, Wbt, att_src, att_dst, x16, a_src,
                                       a_dst);
  k_scanA<<<NB, 256, 0, stream>>>(hist, bsum);
  k_scanB<<<1, 256, 0, stream>>>(bsum, boff, ptr);
  k_scanC<<<NB, 256, 0, stream>>>(hist, boff, ptr, cursor);
  k_edge_perm<<<(EE + 255) / 256, 256, 0, stream>>>(eatt, ei, a_src, a_dst,
                                                    v_edge, cursor, recs,
                                                    t_lin);
  k_gat<<<NN / 4, 256, 0, stream>>>(ptr, recs, x16, out_acc, rinv);
  k_att<<<(EE + 255) / 256, 256, 0, stream>>>(ei, t_lin, rinv, att_out);
  k_stats<<<GG, 256, 0, stream>>>(batch, out_acc, bias, gns, mean_s, istd);
  k_final<<<NN / 4, 256, 0, stream>>>(batch, out_acc, bias, mean_s, istd, gnw,
                                      gnb, y_out);
}

// Round 3
// 331.767 us; speedup vs baseline: 1.1227x; 1.1227x over previous
//
#include <hip/hip_runtime.h>
#include <math.h>

#define NN 50000
#define EE 800000
#define HH 4
#define CC 64
#define DE 16
#define GG 64
#define HC 256          // H*C
#define NEG 0.2f
#define EPSV 1e-5f
#define NB 196          // scan blocks: 196*256 = 50176 >= NN
#define SB 16           // stats sub-blocks per group

typedef __attribute__((ext_vector_type(8))) short short8;
typedef __attribute__((ext_vector_type(4))) float f32x4;

__device__ __forceinline__ unsigned short f2bf(float f) {
  unsigned int x = __float_as_uint(f);
  unsigned int r = (x + 0x7fff + ((x >> 16) & 1)) >> 16;  // round-nearest-even
  return (unsigned short)r;
}
__device__ __forceinline__ float lrelu(float a) {
  return fmaxf(a, 0.f) + NEG * fminf(a, 0.f);
}

// K0: blocks 0..63 (b = k index): Wbt[t][k] = bf16(W[k][colmap(t)]),
//     colmap(t)=(t&3)*64+(t>>2) (so x16 = node @ Wb lands in [n][c][h] order).
//     Transposed layout: B fragment for MFMA is one contiguous ushort8.
//     block 64: v_edge[d][h] = sum_c We[d][h*C+c]*att_edge[h][c].
__global__ __launch_bounds__(256) void k_prep(
    const float* __restrict__ W, const float* __restrict__ We,
    const float* __restrict__ ae_, unsigned short* __restrict__ Wbt,
    float* __restrict__ v_edge) {
  int b = blockIdx.x, t = threadIdx.x;
  if (b < 64) {
    Wbt[(size_t)t * 64 + b] = f2bf(W[b * HC + (t & 3) * 64 + (t >> 2)]);
  } else if (t < DE * HH) {
    int d = t >> 2, h = t & 3;
    float s = 0.f;
    for (int c = 0; c < CC; ++c) s += We[d * HC + h * CC + c] * ae_[h * CC + c];
    v_edge[t] = s;
  }
}

// K1: MFMA projection. One block = 16 rows x 256 cols (4 waves x 4 col-tiles,
// 2 MFMAs each, K=64). Fused per-node logits a_src/a_dst from the fp32
// accumulator (shfl_xor + small LDS reduce). Verified gfx950 layouts:
// A[m=lane&15][k=quad*8+j], B[k=quad*8+j][n=lane&15], C col=lane&15,row=quad*4+r.
// B fragments load as two 16B ushort8 from the transposed Wbt.
__global__ __launch_bounds__(256) void k_xproj(
    const float* __restrict__ node, const unsigned short* __restrict__ Wbt,
    const float* __restrict__ att_src, const float* __restrict__ att_dst,
    unsigned short* __restrict__ x16, float* __restrict__ a_src,
    float* __restrict__ a_dst) {
  int lane = threadIdx.x & 63;
  int w = threadIdx.x >> 6;
  int m = lane & 15, quad = lane >> 4;
  int m0 = blockIdx.x * 16;
  const float* arow = node + (size_t)(m0 + m) * CC + quad * 8;
  float4 af0 = *(const float4*)(arow);
  float4 af1 = *(const float4*)(arow + 4);
  float4 af2 = *(const float4*)(arow + 32);
  float4 af3 = *(const float4*)(arow + 36);
  short8 a0 = {(short)f2bf(af0.x), (short)f2bf(af0.y), (short)f2bf(af0.z),
               (short)f2bf(af0.w), (short)f2bf(af1.x), (short)f2bf(af1.y),
               (short)f2bf(af1.z), (short)f2bf(af1.w)};
  short8 a1 = {(short)f2bf(af2.x), (short)f2bf(af2.y), (short)f2bf(af2.z),
               (short)f2bf(af2.w), (short)f2bf(af3.x), (short)f2bf(af3.y),
               (short)f2bf(af3.z), (short)f2bf(af3.w)};
  float sa[4] = {0, 0, 0, 0}, sd[4] = {0, 0, 0, 0};
#pragma unroll
  for (int i = 0; i < 4; ++i) {
    int t = (w * 4 + i) * 16 + m;
    const unsigned short* bp = Wbt + (size_t)t * 64 + quad * 8;
    short8 b0 = *(const short8*)(bp);
    short8 b1 = *(const short8*)(bp + 32);
    f32x4 acc = {0.f, 0.f, 0.f, 0.f};
    acc = __builtin_amdgcn_mfma_f32_16x16x32_bf16(a0, b0, acc, 0, 0, 0);
    acc = __builtin_amdgcn_mfma_f32_16x16x32_bf16(a1, b1, acc, 0, 0, 0);
    float us_t = att_src[(t & 3) * CC + (t >> 2)];
    float ud_t = att_dst[(t & 3) * CC + (t >> 2)];
#pragma unroll
    for (int r = 0; r < 4; ++r) {
      x16[(size_t)(m0 + quad * 4 + r) * HC + t] = f2bf(acc[r]);
      sa[r] += acc[r] * us_t;
      sd[r] += acc[r] * ud_t;
    }
  }
  __shared__ float lss[4][16][4], lsd[4][16][4];
#pragma unroll
  for (int r = 0; r < 4; ++r) {
    sa[r] += __shfl_xor(sa[r], 4);
    sa[r] += __shfl_xor(sa[r], 8);
    sd[r] += __shfl_xor(sd[r], 4);
    sd[r] += __shfl_xor(sd[r], 8);
  }
  if ((lane & 12) == 0) {
#pragma unroll
    for (int r = 0; r < 4; ++r) {
      lss[w][quad * 4 + r][lane & 3] = sa[r];
      lsd[w][quad * 4 + r][lane & 3] = sd[r];
    }
  }
  __syncthreads();
  int t = threadIdx.x;
  if (t < 64) {
    int row = t >> 2, h = t & 3;
    a_src[(size_t)(m0 + row) * 4 + h] =
        lss[0][row][h] + lss[1][row][h] + lss[2][row][h] + lss[3][row][h];
    a_dst[(size_t)(m0 + row) * 4 + h] =
        lsd[0][row][h] + lsd[1][row][h] + lsd[2][row][h] + lsd[3][row][h];
  }
}

// K2: dst histogram.
__global__ __launch_bounds__(256) void k_hist(
    const int* __restrict__ ei, int* __restrict__ hist) {
  int e = blockIdx.x * 256 + threadIdx.x;
  if (e >= EE) return;
  atomicAdd(&hist[ei[EE + e]], 1);
}

// K3a: coalesced per-block sums of the histogram.
__global__ __launch_bounds__(256) void k_scanA(
    const int* __restrict__ hist, int* __restrict__ bsum) {
  __shared__ int s[256];
  int t = threadIdx.x;
  int idx = blockIdx.x * 256 + t;
  s[t] = (idx < NN) ? hist[idx] : 0;
  __syncthreads();
  for (int d = 128; d; d >>= 1) {
    if (t < d) s[t] += s[t + d];
    __syncthreads();
  }
  if (t == 0) bsum[blockIdx.x] = s[0];
}

// K3b: single block: exclusive scan of NB block sums.
__global__ __launch_bounds__(256) void k_scanB(
    const int* __restrict__ bsum, int* __restrict__ boff,
    int* __restrict__ ptr) {
  __shared__ int s[256];
  int t = threadIdx.x;
  int v = (t < NB) ? bsum[t] : 0;
  s[t] = v;
  __syncthreads();
  for (int d = 1; d < 256; d <<= 1) {
    int u = (t >= d) ? s[t - d] : 0;
    __syncthreads();
    s[t] += u;
    __syncthreads();
  }
  if (t < NB) boff[t] = s[t] - v;
  if (t == 255) ptr[NN] = s[255];
}

// K3c: per-block exclusive scan + block offset -> ptr, cursor.
__global__ __launch_bounds__(256) void k_scanC(
    const int* __restrict__ hist, const int* __restrict__ boff,
    int* __restrict__ ptr, int* __restrict__ cursor) {
  __shared__ int s[256];
  int t = threadIdx.x;
  int idx = blockIdx.x * 256 + t;
  int v = (idx < NN) ? hist[idx] : 0;
  s[t] = v;
  __syncthreads();
  for (int d = 1; d < 256; d <<= 1) {
    int u = (t >= d) ? s[t - d] : 0;
    __syncthreads();
    s[t] += u;
    __syncthreads();
  }
  if (idx < NN) {
    int p = boff[blockIdx.x] + s[t] - v;
    ptr[idx] = p;
    cursor[idx] = p;
  }
}

// K4: fused edge pass: t = exp(lrelu(a_src[sn]+a_dst[dn]+edge_attr@v)), then
// scatter ONE packed uint4 {bf16 t0..t3, sn, e} into the dst-sorted slot.
// Also writes t_lin[e] (coalesced) so the att output can be produced by a
// coalesced kernel instead of a scattered write from k_gat.
__global__ __launch_bounds__(256) void k_edge_perm(
    const float* __restrict__ edge_attr, const int* __restrict__ ei,
    const float* __restrict__ a_src, const float* __restrict__ a_dst,
    const float* __restrict__ v_edge, int* __restrict__ cursor,
    uint4* __restrict__ recs, uint2* __restrict__ t_lin) {
  __shared__ float vs[DE * HH];
  int t = threadIdx.x;
  if (t < DE * HH) vs[t] = v_edge[t];
  __syncthreads();
  int e = blockIdx.x * 256 + t;
  if (e >= EE) return;
  const float4* ea4 = (const float4*)(edge_attr + (size_t)e * DE);
  float ae[4] = {0, 0, 0, 0};
#pragma unroll
  for (int dd = 0; dd < 4; ++dd) {
    float4 ev = ea4[dd];
    float evs[4] = {ev.x, ev.y, ev.z, ev.w};
#pragma unroll
    for (int j = 0; j < 4; ++j) {
      int d = dd * 4 + j;
#pragma unroll
      for (int h = 0; h < 4; ++h) ae[h] += evs[j] * vs[d * 4 + h];
    }
  }
  int sn = ei[e], dn = ei[EE + e];
  float4 as4 = *(const float4*)(a_src + (size_t)sn * 4);
  float4 ad4 = *(const float4*)(a_dst + (size_t)dn * 4);
  float t0 = __expf(lrelu(as4.x + ad4.x + ae[0]));
  float t1 = __expf(lrelu(as4.y + ad4.y + ae[1]));
  float t2 = __expf(lrelu(as4.z + ad4.z + ae[2]));
  float t3 = __expf(lrelu(as4.w + ad4.w + ae[3]));
  uint4 rec;
  rec.x = (unsigned int)f2bf(t0) | ((unsigned int)f2bf(t1) << 16);
  rec.y = (unsigned int)f2bf(t2) | ((unsigned int)f2bf(t3) << 16);
  rec.z = (unsigned int)sn;
  rec.w = (unsigned int)e;
  uint2 tl;
  tl.x = rec.x;
  tl.y = rec.y;
  t_lin[e] = tl;
  int pos = atomicAdd(&cursor[dn], 1);
  recs[pos] = rec;
}

// K5: one wave per dst node. Batched 4 edges/iteration: 4 independent 16B rec
// loads then 4 independent 512B row gathers in flight (x2 via unroll) to cover
// L2/HBM gather latency. Emits out_acc + per-node 1/denom (rinv); att output
// moved to coalesced k_att.
__global__ __launch_bounds__(256) void k_gat(
    const int* __restrict__ ptr, const uint4* __restrict__ recs,
    const unsigned short* __restrict__ x16, float* __restrict__ out_acc,
    float* __restrict__ rinv) {
  int lane = threadIdx.x & 63;
  int w = threadIdx.x >> 6;
  int v = blockIdx.x * 4 + w;
  int start = ptr[v], end = ptr[v + 1];
  float d0 = 0.f, d1 = 0.f, d2 = 0.f, d3 = 0.f;
  float acc0 = 0.f, acc1 = 0.f, acc2 = 0.f, acc3 = 0.f;
  const unsigned short* xb = x16 + lane * 4;
  int j = start;
#pragma unroll 2
  for (; j + 4 <= end; j += 4) {
    uint4 r0 = recs[j];
    uint4 r1 = recs[j + 1];
    uint4 r2 = recs[j + 2];
    uint4 r3 = recs[j + 3];
    uint2 u0 = *(const uint2*)(xb + (size_t)r0.z * HC);
    uint2 u1 = *(const uint2*)(xb + (size_t)r1.z * HC);
    uint2 u2 = *(const uint2*)(xb + (size_t)r2.z * HC);
    uint2 u3 = *(const uint2*)(xb + (size_t)r3.z * HC);
    {
      float t0 = __uint_as_float(r0.x << 16);
      float t1 = __uint_as_float(r0.x & 0xffff0000u);
      float t2 = __uint_as_float(r0.y << 16);
      float t3 = __uint_as_float(r0.y & 0xffff0000u);
      d0 += t0; d1 += t1; d2 += t2; d3 += t3;
      acc0 += t0 * __uint_as_float(u0.x << 16);
      acc1 += t1 * __uint_as_float(u0.x & 0xffff0000u);
      acc2 += t2 * __uint_as_float(u0.y << 16);
      acc3 += t3 * __uint_as_float(u0.y & 0xffff0000u);
    }
    {
      float t0 = __uint_as_float(r1.x << 16);
      float t1 = __uint_as_float(r1.x & 0xffff0000u);
      float t2 = __uint_as_float(r1.y << 16);
      float t3 = __uint_as_float(r1.y & 0xffff0000u);
      d0 += t0; d1 += t1; d2 += t2; d3 += t3;
      acc0 += t0 * __uint_as_float(u1.x << 16);
      acc1 += t1 * __uint_as_float(u1.x & 0xffff0000u);
      acc2 += t2 * __uint_as_float(u1.y << 16);
      acc3 += t3 * __uint_as_float(u1.y & 0xffff0000u);
    }
    {
      float t0 = __uint_as_float(r2.x << 16);
      float t1 = __uint_as_float(r2.x & 0xffff0000u);
      float t2 = __uint_as_float(r2.y << 16);
      float t3 = __uint_as_float(r2.y & 0xffff0000u);
      d0 += t0; d1 += t1; d2 += t2; d3 += t3;
      acc0 += t0 * __uint_as_float(u2.x << 16);
      acc1 += t1 * __uint_as_float(u2.x & 0xffff0000u);
      acc2 += t2 * __uint_as_float(u2.y << 16);
      acc3 += t3 * __uint_as_float(u2.y & 0xffff0000u);
    }
    {
      float t0 = __uint_as_float(r3.x << 16);
      float t1 = __uint_as_float(r3.x & 0xffff0000u);
      float t2 = __uint_as_float(r3.y << 16);
      float t3 = __uint_as_float(r3.y & 0xffff0000u);
      d0 += t0; d1 += t1; d2 += t2; d3 += t3;
      acc0 += t0 * __uint_as_float(u3.x << 16);
      acc1 += t1 * __uint_as_float(u3.x & 0xffff0000u);
      acc2 += t2 * __uint_as_float(u3.y << 16);
      acc3 += t3 * __uint_as_float(u3.y & 0xffff0000u);
    }
  }
  for (; j < end; ++j) {
    uint4 rec = recs[j];
    float t0 = __uint_as_float(rec.x << 16);
    float t1 = __uint_as_float(rec.x & 0xffff0000u);
    float t2 = __uint_as_float(rec.y << 16);
    float t3 = __uint_as_float(rec.y & 0xffff0000u);
    uint2 u = *(const uint2*)(xb + (size_t)rec.z * HC);
    d0 += t0; d1 += t1; d2 += t2; d3 += t3;
    acc0 += t0 * __uint_as_float(u.x << 16);
    acc1 += t1 * __uint_as_float(u.x & 0xffff0000u);
    acc2 += t2 * __uint_as_float(u.y << 16);
    acc3 += t3 * __uint_as_float(u.y & 0xffff0000u);
  }
  float r0 = 1.f / (d0 + 1e-16f), r1 = 1.f / (d1 + 1e-16f);
  float r2 = 1.f / (d2 + 1e-16f), r3 = 1.f / (d3 + 1e-16f);
  out_acc[(size_t)v * CC + lane] =
      0.25f * (r0 * acc0 + r1 * acc1 + r2 * acc2 + r3 * acc3);
  if (lane == 0)
    *(float4*)(rinv + (size_t)v * 4) = make_float4(r0, r1, r2, r3);
}

// K5b: coalesced att output: att[e] = bf16(t[e]) * rinv[dst[e]].
__global__ __launch_bounds__(256) void k_att(
    const int* __restrict__ ei, const uint2* __restrict__ t_lin,
    const float* __restrict__ rinv, float* __restrict__ att_out) {
  int e = blockIdx.x * 256 + threadIdx.x;
  if (e >= EE) return;
  uint2 tl = t_lin[e];
  int dn = ei[EE + e];
  float4 r = *(const float4*)(rinv + (size_t)dn * 4);
  float t0 = __uint_as_float(tl.x << 16);
  float t1 = __uint_as_float(tl.x & 0xffff0000u);
  float t2 = __uint_as_float(tl.y << 16);
  float t3 = __uint_as_float(tl.y & 0xffff0000u);
  *(float4*)(att_out + (size_t)e * 4) =
      make_float4(t0 * r.x, t1 * r.y, t2 * r.z, t3 * r.w);
}

// K6a: GraphNorm partial sums. grid (GG, SB): each block reduces the sb-th
// chunk of group g into p1/p2[(g*SB+sb)*64 + lane]. 1024 blocks -> full
// machine coverage (old single-stage version used 64 blocks = 2% occupancy).
__global__ __launch_bounds__(256) void k_statsA(
    const int* __restrict__ batch, const float* __restrict__ out_acc,
    const float* __restrict__ bias, float* __restrict__ p1,
    float* __restrict__ p2) {
  int g = blockIdx.x, sb = blockIdx.y;
  int lane = threadIdx.x & 63;
  int w = threadIdx.x >> 6;
  int lo = 0, hi = NN;
  while (lo < hi) {
    int mid = (lo + hi) >> 1;
    if (batch[mid] < g) lo = mid + 1; else hi = mid;
  }
  int start = lo;
  hi = NN;
  while (lo < hi) {
    int mid = (lo + hi) >> 1;
    if (batch[mid] < g + 1) lo = mid + 1; else hi = mid;
  }
  int end = lo;
  int cnt = end - start;
  int chunk = (cnt + SB - 1) / SB;
  int c0 = start + sb * chunk;
  int c1 = min(c0 + chunk, end);
  float b = bias[lane];
  float s1 = 0.f, s2 = 0.f;
  for (int n = c0 + w; n < c1; n += 4) {
    float v = out_acc[(size_t)n * CC + lane] + b;
    s1 += v;
    s2 += v * v;
  }
  __shared__ float l1[4][64], l2[4][64];
  l1[w][lane] = s1;
  l2[w][lane] = s2;
  __syncthreads();
  if (w == 0) {
    s1 = l1[0][lane] + l1[1][lane] + l1[2][lane] + l1[3][lane];
    s2 = l2[0][lane] + l2[1][lane] + l2[2][lane] + l2[3][lane];
    p1[(size_t)(g * SB + sb) * 64 + lane] = s1;
    p2[(size_t)(g * SB + sb) * 64 + lane] = s2;
  }
}

// K6b: combine SB partials per group, compute mean_s/istd (same math as the
// old k_stats epilogue).
__global__ __launch_bounds__(64) void k_statsB(
    const int* __restrict__ batch, const float* __restrict__ p1,
    const float* __restrict__ p2, const float* __restrict__ gns,
    float* __restrict__ mean_s, float* __restrict__ istd) {
  int g = blockIdx.x;
  int lane = threadIdx.x;
  int lo = 0, hi = NN;
  while (lo < hi) {
    int mid = (lo + hi) >> 1;
    if (batch[mid] < g) lo = mid + 1; else hi = mid;
  }
  int start = lo;
  hi = NN;
  while (lo < hi) {
    int mid = (lo + hi) >> 1;
    if (batch[mid] < g + 1) lo = mid + 1; else hi = mid;
  }
  int end = lo;
  float s1 = 0.f, s2 = 0.f;
#pragma unroll
  for (int sb = 0; sb < SB; ++sb) {
    s1 += p1[(size_t)(g * SB + sb) * 64 + lane];
    s2 += p2[(size_t)(g * SB + sb) * 64 + lane];
  }
  float c = fmaxf((float)(end - start), 1.0f);
  float mean = s1 / c;
  float ms = mean * gns[lane];
  float var = s2 / c - 2.f * ms * mean + ms * ms;
  mean_s[g * CC + lane] = ms;
  istd[g * CC + lane] = rsqrtf(var + EPSV);
}

// K7: normalize + affine + relu -> y
__global__ __launch_bounds__(256) void k_final(
    const int* __restrict__ batch, const float* __restrict__ out_acc,
    const float* __restrict__ bias, const float* __restrict__ mean_s,
    const float* __restrict__ istd, const float* __restrict__ gnw,
    const float* __restrict__ gnb, float* __restrict__ y) {
  int lane = threadIdx.x & 63;
  int n = blockIdx.x * 4 + (threadIdx.x >> 6);
  int g = batch[n];
  float v = out_acc[(size_t)n * CC + lane] + bias[lane];
  float o = (v - mean_s[g * CC + lane]) * istd[g * CC + lane];
  float r = gnw[lane] * o + gnb[lane];
  y[(size_t)n * CC + lane] = fmaxf(r, 0.0f);
}

extern "C" void kernel_launch(void* const* d_in, const int* in_sizes, int n_in,
                              void* d_out, int out_size, void* d_ws, size_t ws_size,
                              hipStream_t stream) {
  const float* node = (const float*)d_in[0];
  const int* ei = (const int*)d_in[1];
  const float* eatt = (const float*)d_in[2];
  const int* batch = (const int*)d_in[3];
  const float* W = (const float*)d_in[4];
  const float* We = (const float*)d_in[5];
  const float* att_src = (const float*)d_in[6];
  const float* att_dst = (const float*)d_in[7];
  const float* att_edge = (const float*)d_in[8];
  const float* bias = (const float*)d_in[9];
  const float* gnw = (const float*)d_in[10];
  const float* gnb = (const float*)d_in[11];
  const float* gns = (const float*)d_in[12];

  float* ws = (float*)d_ws;
  size_t off = 0;
  uint4* recs = (uint4*)(ws + off);  off += (size_t)EE * 4;  // 12.8 MB
  float* a_src = ws + off;    off += (size_t)NN * HH;
  float* a_dst = ws + off;    off += (size_t)NN * HH;
  float* v_edge = ws + off;   off += 64;
  float* mean_s = ws + off;   off += GG * CC;
  float* istd = ws + off;     off += GG * CC;
  float* out_acc = ws + off;  off += (size_t)NN * CC;
  float* rinv = ws + off;     off += (size_t)NN * HH;     // 0.8 MB
  float* p1 = ws + off;       off += (size_t)GG * SB * 64; // 256 KB
  float* p2 = ws + off;       off += (size_t)GG * SB * 64; // 256 KB
  uint2* t_lin = (uint2*)(ws + off);
  off += (size_t)EE * 2;                                  // 6.4 MB
  unsigned short* x16 = (unsigned short*)(ws + off);
  off += (size_t)NN * HC / 2;                             // 12.8M ushort
  unsigned short* Wbt = (unsigned short*)(ws + off);
  off += (size_t)CC * HC / 2;                             // 16K ushort
  int* iws = (int*)(ws + off);
  size_t ioff = 0;
  int* hist = iws + ioff;     ioff += NN;
  int* ptr = iws + ioff;      ioff += NN + 1;
  int* cursor = iws + ioff;   ioff += NN;
  int* bsum = iws + ioff;     ioff += NB;
  int* boff = iws + ioff;     ioff += NB;

  hipMemsetAsync(hist, 0, NN * sizeof(int), stream);

  float* y_out = (float*)d_out;
  float* att_out = (float*)d_out + (size_t)NN * CC;

  k_prep<<<65, 256, 0, stream>>>(W, We, att_edge, Wbt, v_edge);
  k_hist<<<(EE + 255) / 256, 256, 0, stream>>>(ei, hist);
  k_xproj<<<NN / 16, 256, 0, stream>>>(node, Wbt, att_src, att_dst, x16, a_src,
                                       a_dst);
  k_scanA<<<NB, 256, 0, stream>>>(hist, bsum);
  k_scanB<<<1, 256, 0, stream>>>(bsum, boff, ptr);
  k_scanC<<<NB, 256, 0, stream>>>(hist, boff, ptr, cursor);
  k_edge_perm<<<(EE + 255) / 256, 256, 0, stream>>>(eatt, ei, a_src, a_dst,
                                                    v_edge, cursor, recs,
                                                    t_lin);
  k_gat<<<NN / 4, 256, 0, stream>>>(ptr, recs, x16, out_acc, rinv);
  k_att<<<(EE + 255) / 256, 256, 0, stream>>>(ei, t_lin, rinv, att_out);
  k_statsA<<<dim3(GG, SB), 256, 0, stream>>>(batch, out_acc, bias, p1, p2);
  k_statsB<<<GG, 64, 0, stream>>>(batch, p1, p2, gns, mean_s, istd);
  k_final<<<NN / 4, 256, 0, stream>>>(batch, out_acc, bias, mean_s, istd, gnw,
                                      gnb, y_out);
}

// Round 4
// 328.972 us; speedup vs baseline: 1.1322x; 1.0085x over previous
//
#include <hip/hip_runtime.h>
#include <math.h>

#define NN 50000
#define EE 800000
#define HH 4
#define CC 64
#define DE 16
#define GG 64
#define HC 256          // H*C
#define NEG 0.2f
#define EPSV 1e-5f
#define NB 196          // scan blocks: 196*256 = 50176 >= NN
#define SB 16           // stats sub-blocks per group

typedef __attribute__((ext_vector_type(8))) short short8;
typedef __attribute__((ext_vector_type(4))) float f32x4;
typedef __attribute__((ext_vector_type(2))) float f32x2;

__device__ __forceinline__ unsigned short f2bf(float f) {
  unsigned int x = __float_as_uint(f);
  unsigned int r = (x + 0x7fff + ((x >> 16) & 1)) >> 16;  // round-nearest-even
  return (unsigned short)r;
}
__device__ __forceinline__ float lrelu(float a) {
  return fmaxf(a, 0.f) + NEG * fminf(a, 0.f);
}

// K0: blocks 0..63 (b = k index): Wbt[t][k] = bf16(W[k][colmap(t)]),
//     colmap(t)=(t&3)*64+(t>>2) (so x16 = node @ Wb lands in [n][c][h] order).
//     Transposed layout: B fragment for MFMA is one contiguous ushort8.
//     block 64: v_edge[d][h] = sum_c We[d][h*C+c]*att_edge[h][c].
__global__ __launch_bounds__(256) void k_prep(
    const float* __restrict__ W, const float* __restrict__ We,
    const float* __restrict__ ae_, unsigned short* __restrict__ Wbt,
    float* __restrict__ v_edge) {
  int b = blockIdx.x, t = threadIdx.x;
  if (b < 64) {
    Wbt[(size_t)t * 64 + b] = f2bf(W[b * HC + (t & 3) * 64 + (t >> 2)]);
  } else if (t < DE * HH) {
    int d = t >> 2, h = t & 3;
    float s = 0.f;
    for (int c = 0; c < CC; ++c) s += We[d * HC + h * CC + c] * ae_[h * CC + c];
    v_edge[t] = s;
  }
}

// K1: MFMA projection. One block = 16 rows x 256 cols (4 waves x 4 col-tiles,
// 2 MFMAs each, K=64). Fused per-node logits a_src/a_dst from the fp32
// accumulator (shfl_xor + small LDS reduce). Verified gfx950 layouts:
// A[m=lane&15][k=quad*8+j], B[k=quad*8+j][n=lane&15], C col=lane&15,row=quad*4+r.
// B fragments load as two 16B ushort8 from the transposed Wbt.
__global__ __launch_bounds__(256) void k_xproj(
    const float* __restrict__ node, const unsigned short* __restrict__ Wbt,
    const float* __restrict__ att_src, const float* __restrict__ att_dst,
    unsigned short* __restrict__ x16, float* __restrict__ a_src,
    float* __restrict__ a_dst) {
  int lane = threadIdx.x & 63;
  int w = threadIdx.x >> 6;
  int m = lane & 15, quad = lane >> 4;
  int m0 = blockIdx.x * 16;
  const float* arow = node + (size_t)(m0 + m) * CC + quad * 8;
  float4 af0 = *(const float4*)(arow);
  float4 af1 = *(const float4*)(arow + 4);
  float4 af2 = *(const float4*)(arow + 32);
  float4 af3 = *(const float4*)(arow + 36);
  short8 a0 = {(short)f2bf(af0.x), (short)f2bf(af0.y), (short)f2bf(af0.z),
               (short)f2bf(af0.w), (short)f2bf(af1.x), (short)f2bf(af1.y),
               (short)f2bf(af1.z), (short)f2bf(af1.w)};
  short8 a1 = {(short)f2bf(af2.x), (short)f2bf(af2.y), (short)f2bf(af2.z),
               (short)f2bf(af2.w), (short)f2bf(af3.x), (short)f2bf(af3.y),
               (short)f2bf(af3.z), (short)f2bf(af3.w)};
  float sa[4] = {0, 0, 0, 0}, sd[4] = {0, 0, 0, 0};
#pragma unroll
  for (int i = 0; i < 4; ++i) {
    int t = (w * 4 + i) * 16 + m;
    const unsigned short* bp = Wbt + (size_t)t * 64 + quad * 8;
    short8 b0 = *(const short8*)(bp);
    short8 b1 = *(const short8*)(bp + 32);
    f32x4 acc = {0.f, 0.f, 0.f, 0.f};
    acc = __builtin_amdgcn_mfma_f32_16x16x32_bf16(a0, b0, acc, 0, 0, 0);
    acc = __builtin_amdgcn_mfma_f32_16x16x32_bf16(a1, b1, acc, 0, 0, 0);
    float us_t = att_src[(t & 3) * CC + (t >> 2)];
    float ud_t = att_dst[(t & 3) * CC + (t >> 2)];
#pragma unroll
    for (int r = 0; r < 4; ++r) {
      x16[(size_t)(m0 + quad * 4 + r) * HC + t] = f2bf(acc[r]);
      sa[r] += acc[r] * us_t;
      sd[r] += acc[r] * ud_t;
    }
  }
  __shared__ float lss[4][16][4], lsd[4][16][4];
#pragma unroll
  for (int r = 0; r < 4; ++r) {
    sa[r] += __shfl_xor(sa[r], 4);
    sa[r] += __shfl_xor(sa[r], 8);
    sd[r] += __shfl_xor(sd[r], 4);
    sd[r] += __shfl_xor(sd[r], 8);
  }
  if ((lane & 12) == 0) {
#pragma unroll
    for (int r = 0; r < 4; ++r) {
      lss[w][quad * 4 + r][lane & 3] = sa[r];
      lsd[w][quad * 4 + r][lane & 3] = sd[r];
    }
  }
  __syncthreads();
  int t = threadIdx.x;
  if (t < 64) {
    int row = t >> 2, h = t & 3;
    a_src[(size_t)(m0 + row) * 4 + h] =
        lss[0][row][h] + lss[1][row][h] + lss[2][row][h] + lss[3][row][h];
    a_dst[(size_t)(m0 + row) * 4 + h] =
        lsd[0][row][h] + lsd[1][row][h] + lsd[2][row][h] + lsd[3][row][h];
  }
}

// K2: dst histogram.
__global__ __launch_bounds__(256) void k_hist(
    const int* __restrict__ ei, int* __restrict__ hist) {
  int e = blockIdx.x * 256 + threadIdx.x;
  if (e >= EE) return;
  atomicAdd(&hist[ei[EE + e]], 1);
}

// K3a: coalesced per-block sums of the histogram.
__global__ __launch_bounds__(256) void k_scanA(
    const int* __restrict__ hist, int* __restrict__ bsum) {
  __shared__ int s[256];
  int t = threadIdx.x;
  int idx = blockIdx.x * 256 + t;
  s[t] = (idx < NN) ? hist[idx] : 0;
  __syncthreads();
  for (int d = 128; d; d >>= 1) {
    if (t < d) s[t] += s[t + d];
    __syncthreads();
  }
  if (t == 0) bsum[blockIdx.x] = s[0];
}

// K3b: single block: exclusive scan of NB block sums.
__global__ __launch_bounds__(256) void k_scanB(
    const int* __restrict__ bsum, int* __restrict__ boff,
    int* __restrict__ ptr) {
  __shared__ int s[256];
  int t = threadIdx.x;
  int v = (t < NB) ? bsum[t] : 0;
  s[t] = v;
  __syncthreads();
  for (int d = 1; d < 256; d <<= 1) {
    int u = (t >= d) ? s[t - d] : 0;
    __syncthreads();
    s[t] += u;
    __syncthreads();
  }
  if (t < NB) boff[t] = s[t] - v;
  if (t == 255) ptr[NN] = s[255];
}

// K3c: per-block exclusive scan + block offset -> ptr, cursor.
__global__ __launch_bounds__(256) void k_scanC(
    const int* __restrict__ hist, const int* __restrict__ boff,
    int* __restrict__ ptr, int* __restrict__ cursor) {
  __shared__ int s[256];
  int t = threadIdx.x;
  int idx = blockIdx.x * 256 + t;
  int v = (idx < NN) ? hist[idx] : 0;
  s[t] = v;
  __syncthreads();
  for (int d = 1; d < 256; d <<= 1) {
    int u = (t >= d) ? s[t - d] : 0;
    __syncthreads();
    s[t] += u;
    __syncthreads();
  }
  if (idx < NN) {
    int p = boff[blockIdx.x] + s[t] - v;
    ptr[idx] = p;
    cursor[idx] = p;
  }
}

// K4: fused edge pass: t = exp(lrelu(a_src[sn]+a_dst[dn]+edge_attr@v)), then
// scatter ONE packed uint4 {bf16 t0..t3, sn_byteoff, e} into the dst-sorted
// slot. rec.z is the BYTE offset of row sn in x16 (sn*512) so k_gat can use
// 32-bit voffset addressing. Also writes t_lin[e] (coalesced) for k_att.
__global__ __launch_bounds__(256) void k_edge_perm(
    const float* __restrict__ edge_attr, const int* __restrict__ ei,
    const float* __restrict__ a_src, const float* __restrict__ a_dst,
    const float* __restrict__ v_edge, int* __restrict__ cursor,
    uint4* __restrict__ recs, uint2* __restrict__ t_lin) {
  __shared__ float vs[DE * HH];
  int t = threadIdx.x;
  if (t < DE * HH) vs[t] = v_edge[t];
  __syncthreads();
  int e = blockIdx.x * 256 + t;
  if (e >= EE) return;
  const float4* ea4 = (const float4*)(edge_attr + (size_t)e * DE);
  float ae[4] = {0, 0, 0, 0};
#pragma unroll
  for (int dd = 0; dd < 4; ++dd) {
    float4 ev = ea4[dd];
    float evs[4] = {ev.x, ev.y, ev.z, ev.w};
#pragma unroll
    for (int j = 0; j < 4; ++j) {
      int d = dd * 4 + j;
#pragma unroll
      for (int h = 0; h < 4; ++h) ae[h] += evs[j] * vs[d * 4 + h];
    }
  }
  int sn = ei[e], dn = ei[EE + e];
  float4 as4 = *(const float4*)(a_src + (size_t)sn * 4);
  float4 ad4 = *(const float4*)(a_dst + (size_t)dn * 4);
  float t0 = __expf(lrelu(as4.x + ad4.x + ae[0]));
  float t1 = __expf(lrelu(as4.y + ad4.y + ae[1]));
  float t2 = __expf(lrelu(as4.z + ad4.z + ae[2]));
  float t3 = __expf(lrelu(as4.w + ad4.w + ae[3]));
  uint4 rec;
  rec.x = (unsigned int)f2bf(t0) | ((unsigned int)f2bf(t1) << 16);
  rec.y = (unsigned int)f2bf(t2) | ((unsigned int)f2bf(t3) << 16);
  rec.z = (unsigned int)sn << 9;  // byte offset: sn * HC * sizeof(ushort)
  rec.w = (unsigned int)e;
  uint2 tl;
  tl.x = rec.x;
  tl.y = rec.y;
  t_lin[e] = tl;
  int pos = atomicAdd(&cursor[dn], 1);
  recs[pos] = rec;
}

// K5: one wave per dst node. Batched 4 edges/iteration x unroll 2: 4
// independent 16B rec loads then 4 independent 512B row gathers in flight.
// 32-bit voffset addressing (rec.z is a byte offset) + packed f32x2
// accumulate (v_pk_add/fma_f32) to halve per-edge VALU issue count.
__global__ __launch_bounds__(256) void k_gat(
    const int* __restrict__ ptr, const uint4* __restrict__ recs,
    const unsigned short* __restrict__ x16, float* __restrict__ out_acc,
    float* __restrict__ rinv) {
  int lane = threadIdx.x & 63;
  int w = threadIdx.x >> 6;
  int v = blockIdx.x * 4 + w;
  int start = ptr[v], end = ptr[v + 1];
  f32x2 d01 = {0.f, 0.f}, d23 = {0.f, 0.f};
  f32x2 acc01 = {0.f, 0.f}, acc23 = {0.f, 0.f};
  const char* xbase = (const char*)x16;
  unsigned int lane8 = (unsigned int)lane * 8u;
  int j = start;
#pragma unroll 2
  for (; j + 4 <= end; j += 4) {
    uint4 r0 = recs[j];
    uint4 r1 = recs[j + 1];
    uint4 r2 = recs[j + 2];
    uint4 r3 = recs[j + 3];
    uint2 u0 = *(const uint2*)(xbase + (r0.z + lane8));
    uint2 u1 = *(const uint2*)(xbase + (r1.z + lane8));
    uint2 u2 = *(const uint2*)(xbase + (r2.z + lane8));
    uint2 u3 = *(const uint2*)(xbase + (r3.z + lane8));
#define EDGE_STEP(rn, un)                                              \
    {                                                                  \
      f32x2 ta, tb, xa, xb2;                                           \
      ta.x = __uint_as_float(rn.x << 16);                              \
      ta.y = __uint_as_float(rn.x & 0xffff0000u);                      \
      tb.x = __uint_as_float(rn.y << 16);                              \
      tb.y = __uint_as_float(rn.y & 0xffff0000u);                      \
      xa.x = __uint_as_float(un.x << 16);                              \
      xa.y = __uint_as_float(un.x & 0xffff0000u);                      \
      xb2.x = __uint_as_float(un.y << 16);                             \
      xb2.y = __uint_as_float(un.y & 0xffff0000u);                     \
      d01 += ta;                                                       \
      d23 += tb;                                                       \
      acc01 += ta * xa;                                                \
      acc23 += tb * xb2;                                               \
    }
    EDGE_STEP(r0, u0)
    EDGE_STEP(r1, u1)
    EDGE_STEP(r2, u2)
    EDGE_STEP(r3, u3)
  }
  for (; j < end; ++j) {
    uint4 rec = recs[j];
    uint2 u = *(const uint2*)(xbase + (rec.z + lane8));
    EDGE_STEP(rec, u)
  }
#undef EDGE_STEP
  float r0 = 1.f / (d01.x + 1e-16f), r1 = 1.f / (d01.y + 1e-16f);
  float r2 = 1.f / (d23.x + 1e-16f), r3 = 1.f / (d23.y + 1e-16f);
  out_acc[(size_t)v * CC + lane] =
      0.25f * (r0 * acc01.x + r1 * acc01.y + r2 * acc23.x + r3 * acc23.y);
  if (lane == 0)
    *(float4*)(rinv + (size_t)v * 4) = make_float4(r0, r1, r2, r3);
}

// K5b: coalesced att output: att[e] = bf16(t[e]) * rinv[dst[e]].
__global__ __launch_bounds__(256) void k_att(
    const int* __restrict__ ei, const uint2* __restrict__ t_lin,
    const float* __restrict__ rinv, float* __restrict__ att_out) {
  int e = blockIdx.x * 256 + threadIdx.x;
  if (e >= EE) return;
  uint2 tl = t_lin[e];
  int dn = ei[EE + e];
  float4 r = *(const float4*)(rinv + (size_t)dn * 4);
  float t0 = __uint_as_float(tl.x << 16);
  float t1 = __uint_as_float(tl.x & 0xffff0000u);
  float t2 = __uint_as_float(tl.y << 16);
  float t3 = __uint_as_float(tl.y & 0xffff0000u);
  *(float4*)(att_out + (size_t)e * 4) =
      make_float4(t0 * r.x, t1 * r.y, t2 * r.z, t3 * r.w);
}

// K6a: GraphNorm partial sums. grid (GG, SB): each block reduces the sb-th
// chunk of group g into p1/p2[(g*SB+sb)*64 + lane]. 1024 blocks -> full
// machine coverage.
__global__ __launch_bounds__(256) void k_statsA(
    const int* __restrict__ batch, const float* __restrict__ out_acc,
    const float* __restrict__ bias, float* __restrict__ p1,
    float* __restrict__ p2) {
  int g = blockIdx.x, sb = blockIdx.y;
  int lane = threadIdx.x & 63;
  int w = threadIdx.x >> 6;
  int lo = 0, hi = NN;
  while (lo < hi) {
    int mid = (lo + hi) >> 1;
    if (batch[mid] < g) lo = mid + 1; else hi = mid;
  }
  int start = lo;
  hi = NN;
  while (lo < hi) {
    int mid = (lo + hi) >> 1;
    if (batch[mid] < g + 1) lo = mid + 1; else hi = mid;
  }
  int end = lo;
  int cnt = end - start;
  int chunk = (cnt + SB - 1) / SB;
  int c0 = start + sb * chunk;
  int c1 = min(c0 + chunk, end);
  float b = bias[lane];
  float s1 = 0.f, s2 = 0.f;
  for (int n = c0 + w; n < c1; n += 4) {
    float v = out_acc[(size_t)n * CC + lane] + b;
    s1 += v;
    s2 += v * v;
  }
  __shared__ float l1[4][64], l2[4][64];
  l1[w][lane] = s1;
  l2[w][lane] = s2;
  __syncthreads();
  if (w == 0) {
    s1 = l1[0][lane] + l1[1][lane] + l1[2][lane] + l1[3][lane];
    s2 = l2[0][lane] + l2[1][lane] + l2[2][lane] + l2[3][lane];
    p1[(size_t)(g * SB + sb) * 64 + lane] = s1;
    p2[(size_t)(g * SB + sb) * 64 + lane] = s2;
  }
}

// K6b: combine SB partials per group, compute mean_s/istd (same math as the
// old k_stats epilogue).
__global__ __launch_bounds__(64) void k_statsB(
    const int* __restrict__ batch, const float* __restrict__ p1,
    const float* __restrict__ p2, const float* __restrict__ gns,
    float* __restrict__ mean_s, float* __restrict__ istd) {
  int g = blockIdx.x;
  int lane = threadIdx.x;
  int lo = 0, hi = NN;
  while (lo < hi) {
    int mid = (lo + hi) >> 1;
    if (batch[mid] < g) lo = mid + 1; else hi = mid;
  }
  int start = lo;
  hi = NN;
  while (lo < hi) {
    int mid = (lo + hi) >> 1;
    if (batch[mid] < g + 1) lo = mid + 1; else hi = mid;
  }
  int end = lo;
  float s1 = 0.f, s2 = 0.f;
#pragma unroll
  for (int sb = 0; sb < SB; ++sb) {
    s1 += p1[(size_t)(g * SB + sb) * 64 + lane];
    s2 += p2[(size_t)(g * SB + sb) * 64 + lane];
  }
  float c = fmaxf((float)(end - start), 1.0f);
  float mean = s1 / c;
  float ms = mean * gns[lane];
  float var = s2 / c - 2.f * ms * mean + ms * ms;
  mean_s[g * CC + lane] = ms;
  istd[g * CC + lane] = rsqrtf(var + EPSV);
}

// K7: normalize + affine + relu -> y
__global__ __launch_bounds__(256) void k_final(
    const int* __restrict__ batch, const float* __restrict__ out_acc,
    const float* __restrict__ bias, const float* __restrict__ mean_s,
    const float* __restrict__ istd, const float* __restrict__ gnw,
    const float* __restrict__ gnb, float* __restrict__ y) {
  int lane = threadIdx.x & 63;
  int n = blockIdx.x * 4 + (threadIdx.x >> 6);
  int g = batch[n];
  float v = out_acc[(size_t)n * CC + lane] + bias[lane];
  float o = (v - mean_s[g * CC + lane]) * istd[g * CC + lane];
  float r = gnw[lane] * o + gnb[lane];
  y[(size_t)n * CC + lane] = fmaxf(r, 0.0f);
}

extern "C" void kernel_launch(void* const* d_in, const int* in_sizes, int n_in,
                              void* d_out, int out_size, void* d_ws, size_t ws_size,
                              hipStream_t stream) {
  const float* node = (const float*)d_in[0];
  const int* ei = (const int*)d_in[1];
  const float* eatt = (const float*)d_in[2];
  const int* batch = (const int*)d_in[3];
  const float* W = (const float*)d_in[4];
  const float* We = (const float*)d_in[5];
  const float* att_src = (const float*)d_in[6];
  const float* att_dst = (const float*)d_in[7];
  const float* att_edge = (const float*)d_in[8];
  const float* bias = (const float*)d_in[9];
  const float* gnw = (const float*)d_in[10];
  const float* gnb = (const float*)d_in[11];
  const float* gns = (const float*)d_in[12];

  float* ws = (float*)d_ws;
  size_t off = 0;
  uint4* recs = (uint4*)(ws + off);  off += (size_t)EE * 4;  // 12.8 MB
  float* a_src = ws + off;    off += (size_t)NN * HH;
  float* a_dst = ws + off;    off += (size_t)NN * HH;
  float* v_edge = ws + off;   off += 64;
  float* mean_s = ws + off;   off += GG * CC;
  float* istd = ws + off;     off += GG * CC;
  float* out_acc = ws + off;  off += (size_t)NN * CC;
  float* rinv = ws + off;     off += (size_t)NN * HH;     // 0.8 MB
  float* p1 = ws + off;       off += (size_t)GG * SB * 64; // 256 KB
  float* p2 = ws + off;       off += (size_t)GG * SB * 64; // 256 KB
  uint2* t_lin = (uint2*)(ws + off);
  off += (size_t)EE * 2;                                  // 6.4 MB
  unsigned short* x16 = (unsigned short*)(ws + off);
  off += (size_t)NN * HC / 2;                             // 12.8M ushort
  unsigned short* Wbt = (unsigned short*)(ws + off);
  off += (size_t)CC * HC / 2;                             // 16K ushort
  int* iws = (int*)(ws + off);
  size_t ioff = 0;
  int* hist = iws + ioff;     ioff += NN;
  int* ptr = iws + ioff;      ioff += NN + 1;
  int* cursor = iws + ioff;   ioff += NN;
  int* bsum = iws + ioff;     ioff += NB;
  int* boff = iws + ioff;     ioff += NB;

  hipMemsetAsync(hist, 0, NN * sizeof(int), stream);

  float* y_out = (float*)d_out;
  float* att_out = (float*)d_out + (size_t)NN * CC;

  k_prep<<<65, 256, 0, stream>>>(W, We, att_edge, Wbt, v_edge);
  k_hist<<<(EE + 255) / 256, 256, 0, stream>>>(ei, hist);
  k_xproj<<<NN / 16, 256, 0, stream>>>(node, Wbt, att_src, att_dst, x16, a_src,
                                       a_dst);
  k_scanA<<<NB, 256, 0, stream>>>(hist, bsum);
  k_scanB<<<1, 256, 0, stream>>>(bsum, boff, ptr);
  k_scanC<<<NB, 256, 0, stream>>>(hist, boff, ptr, cursor);
  k_edge_perm<<<(EE + 255) / 256, 256, 0, stream>>>(eatt, ei, a_src, a_dst,
                                                    v_edge, cursor, recs,
                                                    t_lin);
  k_gat<<<NN / 4, 256, 0, stream>>>(ptr, recs, x16, out_acc, rinv);
  k_att<<<(EE + 255) / 256, 256, 0, stream>>>(ei, t_lin, rinv, att_out);
  k_statsA<<<dim3(GG, SB), 256, 0, stream>>>(batch, out_acc, bias, p1, p2);
  k_statsB<<<GG, 64, 0, stream>>>(batch, p1, p2, gns, mean_s, istd);
  k_final<<<NN / 4, 256, 0, stream>>>(batch, out_acc, bias, mean_s, istd, gnw,
                                      gnb, y_out);
}

// Round 5
// 325.377 us; speedup vs baseline: 1.1447x; 1.0110x over previous
//
#include <hip/hip_runtime.h>
#include <math.h>

#define NN 50000
#define EE 800000
#define HH 4
#define CC 64
#define DE 16
#define GG 64
#define HC 256          // H*C
#define NEG 0.2f
#define EPSV 1e-5f
#define NB 196          // scan blocks: 196*256 = 50176 >= NN
#define SB 16           // stats sub-blocks per group

typedef __attribute__((ext_vector_type(8))) short short8;
typedef __attribute__((ext_vector_type(4))) float f32x4;
typedef __attribute__((ext_vector_type(2))) float f32x2;

__device__ __forceinline__ unsigned short f2bf(float f) {
  unsigned int x = __float_as_uint(f);
  unsigned int r = (x + 0x7fff + ((x >> 16) & 1)) >> 16;  // round-nearest-even
  return (unsigned short)r;
}
__device__ __forceinline__ float lrelu(float a) {
  return fmaxf(a, 0.f) + NEG * fminf(a, 0.f);
}

// K0: blocks 0..63 (b = k index): Wbt[t][k] = bf16(W[k][colmap(t)]),
//     colmap(t)=(t&3)*64+(t>>2) (so x16 = node @ Wb lands in [n][c][h] order).
//     Transposed layout: B fragment for MFMA is one contiguous ushort8.
//     block 64: v_edge[d][h] = sum_c We[d][h*C+c]*att_edge[h][c].
__global__ __launch_bounds__(256) void k_prep(
    const float* __restrict__ W, const float* __restrict__ We,
    const float* __restrict__ ae_, unsigned short* __restrict__ Wbt,
    float* __restrict__ v_edge) {
  int b = blockIdx.x, t = threadIdx.x;
  if (b < 64) {
    Wbt[(size_t)t * 64 + b] = f2bf(W[b * HC + (t & 3) * 64 + (t >> 2)]);
  } else if (t < DE * HH) {
    int d = t >> 2, h = t & 3;
    float s = 0.f;
    for (int c = 0; c < CC; ++c) s += We[d * HC + h * CC + c] * ae_[h * CC + c];
    v_edge[t] = s;
  }
}

// K1: MFMA projection. One block = 16 rows x 256 cols (4 waves x 4 col-tiles,
// 2 MFMAs each, K=64). Fused per-node logits a_src/a_dst from the fp32
// accumulator (shfl_xor + small LDS reduce). Verified gfx950 layouts:
// A[m=lane&15][k=quad*8+j], B[k=quad*8+j][n=lane&15], C col=lane&15,row=quad*4+r.
// x16 output now staged through LDS (padded stride 260 ushorts) so global
// stores are coalesced uint4 (was: 16 scalar 2-byte scatter stores/thread).
__global__ __launch_bounds__(256) void k_xproj(
    const float* __restrict__ node, const unsigned short* __restrict__ Wbt,
    const float* __restrict__ att_src, const float* __restrict__ att_dst,
    unsigned short* __restrict__ x16, float* __restrict__ a_src,
    float* __restrict__ a_dst) {
  int lane = threadIdx.x & 63;
  int w = threadIdx.x >> 6;
  int m = lane & 15, quad = lane >> 4;
  int m0 = blockIdx.x * 16;
  __shared__ unsigned short xs[16][260];  // +4 pad: quad rows hit distinct banks
  const float* arow = node + (size_t)(m0 + m) * CC + quad * 8;
  float4 af0 = *(const float4*)(arow);
  float4 af1 = *(const float4*)(arow + 4);
  float4 af2 = *(const float4*)(arow + 32);
  float4 af3 = *(const float4*)(arow + 36);
  short8 a0 = {(short)f2bf(af0.x), (short)f2bf(af0.y), (short)f2bf(af0.z),
               (short)f2bf(af0.w), (short)f2bf(af1.x), (short)f2bf(af1.y),
               (short)f2bf(af1.z), (short)f2bf(af1.w)};
  short8 a1 = {(short)f2bf(af2.x), (short)f2bf(af2.y), (short)f2bf(af2.z),
               (short)f2bf(af2.w), (short)f2bf(af3.x), (short)f2bf(af3.y),
               (short)f2bf(af3.z), (short)f2bf(af3.w)};
  float sa[4] = {0, 0, 0, 0}, sd[4] = {0, 0, 0, 0};
#pragma unroll
  for (int i = 0; i < 4; ++i) {
    int t = (w * 4 + i) * 16 + m;
    const unsigned short* bp = Wbt + (size_t)t * 64 + quad * 8;
    short8 b0 = *(const short8*)(bp);
    short8 b1 = *(const short8*)(bp + 32);
    f32x4 acc = {0.f, 0.f, 0.f, 0.f};
    acc = __builtin_amdgcn_mfma_f32_16x16x32_bf16(a0, b0, acc, 0, 0, 0);
    acc = __builtin_amdgcn_mfma_f32_16x16x32_bf16(a1, b1, acc, 0, 0, 0);
    float us_t = att_src[(t & 3) * CC + (t >> 2)];
    float ud_t = att_dst[(t & 3) * CC + (t >> 2)];
#pragma unroll
    for (int r = 0; r < 4; ++r) {
      xs[quad * 4 + r][t] = f2bf(acc[r]);
      sa[r] += acc[r] * us_t;
      sd[r] += acc[r] * ud_t;
    }
  }
  __shared__ float lss[4][16][4], lsd[4][16][4];
#pragma unroll
  for (int r = 0; r < 4; ++r) {
    sa[r] += __shfl_xor(sa[r], 4);
    sa[r] += __shfl_xor(sa[r], 8);
    sd[r] += __shfl_xor(sd[r], 4);
    sd[r] += __shfl_xor(sd[r], 8);
  }
  if ((lane & 12) == 0) {
#pragma unroll
    for (int r = 0; r < 4; ++r) {
      lss[w][quad * 4 + r][lane & 3] = sa[r];
      lsd[w][quad * 4 + r][lane & 3] = sd[r];
    }
  }
  __syncthreads();
  int t = threadIdx.x;
  if (t < 64) {
    int row = t >> 2, h = t & 3;
    a_src[(size_t)(m0 + row) * 4 + h] =
        lss[0][row][h] + lss[1][row][h] + lss[2][row][h] + lss[3][row][h];
    a_dst[(size_t)(m0 + row) * 4 + h] =
        lsd[0][row][h] + lsd[1][row][h] + lsd[2][row][h] + lsd[3][row][h];
  }
  // coalesced x16 write: 16 rows x 256 cols bf16, 1 KB contiguous per wave
  {
    int row = t >> 4, seg = t & 15;
    const unsigned short* xr = &xs[0][0] + row * 260 + seg * 16;
    uint2 lo = *(const uint2*)(xr);
    uint2 hi = *(const uint2*)(xr + 4);
    uint4 o;
    o.x = lo.x; o.y = lo.y; o.z = hi.x; o.w = hi.y;
    uint4* xg = (uint4*)(x16 + (size_t)m0 * HC);
    xg[row * 32 + seg * 2] = o;
    uint2 lo2 = *(const uint2*)(xr + 8);
    uint2 hi2 = *(const uint2*)(xr + 12);
    uint4 o2;
    o2.x = lo2.x; o2.y = lo2.y; o2.z = hi2.x; o2.w = hi2.y;
    xg[row * 32 + seg * 2 + 1] = o2;
  }
}

// K2: dst histogram, 4 edges/thread via int4.
__global__ __launch_bounds__(256) void k_hist(
    const int* __restrict__ ei, int* __restrict__ hist) {
  int i = blockIdx.x * 256 + threadIdx.x;
  if (i >= EE / 4) return;
  int4 d = ((const int4*)(ei + EE))[i];
  atomicAdd(&hist[d.x], 1);
  atomicAdd(&hist[d.y], 1);
  atomicAdd(&hist[d.z], 1);
  atomicAdd(&hist[d.w], 1);
}

// K3a: coalesced per-block sums of the histogram.
__global__ __launch_bounds__(256) void k_scanA(
    const int* __restrict__ hist, int* __restrict__ bsum) {
  __shared__ int s[256];
  int t = threadIdx.x;
  int idx = blockIdx.x * 256 + t;
  s[t] = (idx < NN) ? hist[idx] : 0;
  __syncthreads();
  for (int d = 128; d; d >>= 1) {
    if (t < d) s[t] += s[t + d];
    __syncthreads();
  }
  if (t == 0) bsum[blockIdx.x] = s[0];
}

// K3b: single block: exclusive scan of NB block sums.
__global__ __launch_bounds__(256) void k_scanB(
    const int* __restrict__ bsum, int* __restrict__ boff,
    int* __restrict__ ptr) {
  __shared__ int s[256];
  int t = threadIdx.x;
  int v = (t < NB) ? bsum[t] : 0;
  s[t] = v;
  __syncthreads();
  for (int d = 1; d < 256; d <<= 1) {
    int u = (t >= d) ? s[t - d] : 0;
    __syncthreads();
    s[t] += u;
    __syncthreads();
  }
  if (t < NB) boff[t] = s[t] - v;
  if (t == 255) ptr[NN] = s[255];
}

// K3c: per-block exclusive scan + block offset -> ptr, cursor.
__global__ __launch_bounds__(256) void k_scanC(
    const int* __restrict__ hist, const int* __restrict__ boff,
    int* __restrict__ ptr, int* __restrict__ cursor) {
  __shared__ int s[256];
  int t = threadIdx.x;
  int idx = blockIdx.x * 256 + t;
  int v = (idx < NN) ? hist[idx] : 0;
  s[t] = v;
  __syncthreads();
  for (int d = 1; d < 256; d <<= 1) {
    int u = (t >= d) ? s[t - d] : 0;
    __syncthreads();
    s[t] += u;
    __syncthreads();
  }
  if (idx < NN) {
    int p = boff[blockIdx.x] + s[t] - v;
    ptr[idx] = p;
    cursor[idx] = p;
  }
}

// K4: fused edge pass: t = exp(lrelu(a_src[sn]+a_dst[dn]+edge_attr@v)), then
// scatter ONE packed uint4 {bf16 t0..t3, sn_byteoff, e} into the dst-sorted
// slot. rec.z is the BYTE offset of row sn in x16 (sn*512) so k_gat can use
// 32-bit voffset addressing. Also writes t_lin[e] (coalesced) for k_att.
__global__ __launch_bounds__(256) void k_edge_perm(
    const float* __restrict__ edge_attr, const int* __restrict__ ei,
    const float* __restrict__ a_src, const float* __restrict__ a_dst,
    const float* __restrict__ v_edge, int* __restrict__ cursor,
    uint4* __restrict__ recs, uint2* __restrict__ t_lin) {
  __shared__ float vs[DE * HH];
  int t = threadIdx.x;
  if (t < DE * HH) vs[t] = v_edge[t];
  __syncthreads();
  int e = blockIdx.x * 256 + t;
  if (e >= EE) return;
  const float4* ea4 = (const float4*)(edge_attr + (size_t)e * DE);
  float ae[4] = {0, 0, 0, 0};
#pragma unroll
  for (int dd = 0; dd < 4; ++dd) {
    float4 ev = ea4[dd];
    float evs[4] = {ev.x, ev.y, ev.z, ev.w};
#pragma unroll
    for (int j = 0; j < 4; ++j) {
      int d = dd * 4 + j;
#pragma unroll
      for (int h = 0; h < 4; ++h) ae[h] += evs[j] * vs[d * 4 + h];
    }
  }
  int sn = ei[e], dn = ei[EE + e];
  float4 as4 = *(const float4*)(a_src + (size_t)sn * 4);
  float4 ad4 = *(const float4*)(a_dst + (size_t)dn * 4);
  float t0 = __expf(lrelu(as4.x + ad4.x + ae[0]));
  float t1 = __expf(lrelu(as4.y + ad4.y + ae[1]));
  float t2 = __expf(lrelu(as4.z + ad4.z + ae[2]));
  float t3 = __expf(lrelu(as4.w + ad4.w + ae[3]));
  uint4 rec;
  rec.x = (unsigned int)f2bf(t0) | ((unsigned int)f2bf(t1) << 16);
  rec.y = (unsigned int)f2bf(t2) | ((unsigned int)f2bf(t3) << 16);
  rec.z = (unsigned int)sn << 9;  // byte offset: sn * HC * sizeof(ushort)
  rec.w = (unsigned int)e;
  uint2 tl;
  tl.x = rec.x;
  tl.y = rec.y;
  t_lin[e] = tl;
  int pos = atomicAdd(&cursor[dn], 1);
  recs[pos] = rec;
}

// K5: one wave per dst node. Batched 4 edges/iteration x unroll 2: 4
// independent 16B rec loads then 4 independent 512B row gathers in flight.
// start/end forced to SGPR via readfirstlane (wave-uniform by construction)
// so rec loads scalarize to s_load and issue ahead on the scalar path.
__global__ __launch_bounds__(256) void k_gat(
    const int* __restrict__ ptr, const uint4* __restrict__ recs,
    const unsigned short* __restrict__ x16, float* __restrict__ out_acc,
    float* __restrict__ rinv) {
  int lane = threadIdx.x & 63;
  int w = threadIdx.x >> 6;
  int v = blockIdx.x * 4 + w;
  int start = __builtin_amdgcn_readfirstlane(ptr[v]);
  int end = __builtin_amdgcn_readfirstlane(ptr[v + 1]);
  f32x2 d01 = {0.f, 0.f}, d23 = {0.f, 0.f};
  f32x2 acc01 = {0.f, 0.f}, acc23 = {0.f, 0.f};
  const char* xbase = (const char*)x16;
  unsigned int lane8 = (unsigned int)lane * 8u;
  int j = start;
#pragma unroll 2
  for (; j + 4 <= end; j += 4) {
    uint4 r0 = recs[j];
    uint4 r1 = recs[j + 1];
    uint4 r2 = recs[j + 2];
    uint4 r3 = recs[j + 3];
    uint2 u0 = *(const uint2*)(xbase + (r0.z + lane8));
    uint2 u1 = *(const uint2*)(xbase + (r1.z + lane8));
    uint2 u2 = *(const uint2*)(xbase + (r2.z + lane8));
    uint2 u3 = *(const uint2*)(xbase + (r3.z + lane8));
#define EDGE_STEP(rn, un)                                              \
    {                                                                  \
      f32x2 ta, tb, xa, xb2;                                           \
      ta.x = __uint_as_float(rn.x << 16);                              \
      ta.y = __uint_as_float(rn.x & 0xffff0000u);                      \
      tb.x = __uint_as_float(rn.y << 16);                              \
      tb.y = __uint_as_float(rn.y & 0xffff0000u);                      \
      xa.x = __uint_as_float(un.x << 16);                              \
      xa.y = __uint_as_float(un.x & 0xffff0000u);                      \
      xb2.x = __uint_as_float(un.y << 16);                             \
      xb2.y = __uint_as_float(un.y & 0xffff0000u);                     \
      d01 += ta;                                                       \
      d23 += tb;                                                       \
      acc01 += ta * xa;                                                \
      acc23 += tb * xb2;                                               \
    }
    EDGE_STEP(r0, u0)
    EDGE_STEP(r1, u1)
    EDGE_STEP(r2, u2)
    EDGE_STEP(r3, u3)
  }
  for (; j < end; ++j) {
    uint4 rec = recs[j];
    uint2 u = *(const uint2*)(xbase + (rec.z + lane8));
    EDGE_STEP(rec, u)
  }
#undef EDGE_STEP
  float r0 = 1.f / (d01.x + 1e-16f), r1 = 1.f / (d01.y + 1e-16f);
  float r2 = 1.f / (d23.x + 1e-16f), r3 = 1.f / (d23.y + 1e-16f);
  out_acc[(size_t)v * CC + lane] =
      0.25f * (r0 * acc01.x + r1 * acc01.y + r2 * acc23.x + r3 * acc23.y);
  if (lane == 0)
    *(float4*)(rinv + (size_t)v * 4) = make_float4(r0, r1, r2, r3);
}

// K5b: coalesced att output: att[e] = bf16(t[e]) * rinv[dst[e]].
__global__ __launch_bounds__(256) void k_att(
    const int* __restrict__ ei, const uint2* __restrict__ t_lin,
    const float* __restrict__ rinv, float* __restrict__ att_out) {
  int e = blockIdx.x * 256 + threadIdx.x;
  if (e >= EE) return;
  uint2 tl = t_lin[e];
  int dn = ei[EE + e];
  float4 r = *(const float4*)(rinv + (size_t)dn * 4);
  float t0 = __uint_as_float(tl.x << 16);
  float t1 = __uint_as_float(tl.x & 0xffff0000u);
  float t2 = __uint_as_float(tl.y << 16);
  float t3 = __uint_as_float(tl.y & 0xffff0000u);
  *(float4*)(att_out + (size_t)e * 4) =
      make_float4(t0 * r.x, t1 * r.y, t2 * r.z, t3 * r.w);
}

// K6a: GraphNorm partial sums. grid (GG, SB): each block reduces the sb-th
// chunk of group g into p1/p2[(g*SB+sb)*64 + lane]. 1024 blocks -> full
// machine coverage.
__global__ __launch_bounds__(256) void k_statsA(
    const int* __restrict__ batch, const float* __restrict__ out_acc,
    const float* __restrict__ bias, float* __restrict__ p1,
    float* __restrict__ p2) {
  int g = blockIdx.x, sb = blockIdx.y;
  int lane = threadIdx.x & 63;
  int w = threadIdx.x >> 6;
  int lo = 0, hi = NN;
  while (lo < hi) {
    int mid = (lo + hi) >> 1;
    if (batch[mid] < g) lo = mid + 1; else hi = mid;
  }
  int start = lo;
  hi = NN;
  while (lo < hi) {
    int mid = (lo + hi) >> 1;
    if (batch[mid] < g + 1) lo = mid + 1; else hi = mid;
  }
  int end = lo;
  int cnt = end - start;
  int chunk = (cnt + SB - 1) / SB;
  int c0 = start + sb * chunk;
  int c1 = min(c0 + chunk, end);
  float b = bias[lane];
  float s1 = 0.f, s2 = 0.f;
  for (int n = c0 + w; n < c1; n += 4) {
    float v = out_acc[(size_t)n * CC + lane] + b;
    s1 += v;
    s2 += v * v;
  }
  __shared__ float l1[4][64], l2[4][64];
  l1[w][lane] = s1;
  l2[w][lane] = s2;
  __syncthreads();
  if (w == 0) {
    s1 = l1[0][lane] + l1[1][lane] + l1[2][lane] + l1[3][lane];
    s2 = l2[0][lane] + l2[1][lane] + l2[2][lane] + l2[3][lane];
    p1[(size_t)(g * SB + sb) * 64 + lane] = s1;
    p2[(size_t)(g * SB + sb) * 64 + lane] = s2;
  }
}

// K6b: combine SB partials per group, compute mean_s/istd (same math as the
// old k_stats epilogue).
__global__ __launch_bounds__(64) void k_statsB(
    const int* __restrict__ batch, const float* __restrict__ p1,
    const float* __restrict__ p2, const float* __restrict__ gns,
    float* __restrict__ mean_s, float* __restrict__ istd) {
  int g = blockIdx.x;
  int lane = threadIdx.x;
  int lo = 0, hi = NN;
  while (lo < hi) {
    int mid = (lo + hi) >> 1;
    if (batch[mid] < g) lo = mid + 1; else hi = mid;
  }
  int start = lo;
  hi = NN;
  while (lo < hi) {
    int mid = (lo + hi) >> 1;
    if (batch[mid] < g + 1) lo = mid + 1; else hi = mid;
  }
  int end = lo;
  float s1 = 0.f, s2 = 0.f;
#pragma unroll
  for (int sb = 0; sb < SB; ++sb) {
    s1 += p1[(size_t)(g * SB + sb) * 64 + lane];
    s2 += p2[(size_t)(g * SB + sb) * 64 + lane];
  }
  float c = fmaxf((float)(end - start), 1.0f);
  float mean = s1 / c;
  float ms = mean * gns[lane];
  float var = s2 / c - 2.f * ms * mean + ms * ms;
  mean_s[g * CC + lane] = ms;
  istd[g * CC + lane] = rsqrtf(var + EPSV);
}

// K7: normalize + affine + relu -> y
__global__ __launch_bounds__(256) void k_final(
    const int* __restrict__ batch, const float* __restrict__ out_acc,
    const float* __restrict__ bias, const float* __restrict__ mean_s,
    const float* __restrict__ istd, const float* __restrict__ gnw,
    const float* __restrict__ gnb, float* __restrict__ y) {
  int lane = threadIdx.x & 63;
  int n = blockIdx.x * 4 + (threadIdx.x >> 6);
  int g = batch[n];
  float v = out_acc[(size_t)n * CC + lane] + bias[lane];
  float o = (v - mean_s[g * CC + lane]) * istd[g * CC + lane];
  float r = gnw[lane] * o + gnb[lane];
  y[(size_t)n * CC + lane] = fmaxf(r, 0.0f);
}

extern "C" void kernel_launch(void* const* d_in, const int* in_sizes, int n_in,
                              void* d_out, int out_size, void* d_ws, size_t ws_size,
                              hipStream_t stream) {
  const float* node = (const float*)d_in[0];
  const int* ei = (const int*)d_in[1];
  const float* eatt = (const float*)d_in[2];
  const int* batch = (const int*)d_in[3];
  const float* W = (const float*)d_in[4];
  const float* We = (const float*)d_in[5];
  const float* att_src = (const float*)d_in[6];
  const float* att_dst = (const float*)d_in[7];
  const float* att_edge = (const float*)d_in[8];
  const float* bias = (const float*)d_in[9];
  const float* gnw = (const float*)d_in[10];
  const float* gnb = (const float*)d_in[11];
  const float* gns = (const float*)d_in[12];

  float* ws = (float*)d_ws;
  size_t off = 0;
  uint4* recs = (uint4*)(ws + off);  off += (size_t)EE * 4;  // 12.8 MB
  float* a_src = ws + off;    off += (size_t)NN * HH;
  float* a_dst = ws + off;    off += (size_t)NN * HH;
  float* v_edge = ws + off;   off += 64;
  float* mean_s = ws + off;   off += GG * CC;
  float* istd = ws + off;     off += GG * CC;
  float* out_acc = ws + off;  off += (size_t)NN * CC;
  float* rinv = ws + off;     off += (size_t)NN * HH;     // 0.8 MB
  float* p1 = ws + off;       off += (size_t)GG * SB * 64; // 256 KB
  float* p2 = ws + off;       off += (size_t)GG * SB * 64; // 256 KB
  uint2* t_lin = (uint2*)(ws + off);
  off += (size_t)EE * 2;                                  // 6.4 MB
  unsigned short* x16 = (unsigned short*)(ws + off);
  off += (size_t)NN * HC / 2;                             // 12.8M ushort
  unsigned short* Wbt = (unsigned short*)(ws + off);
  off += (size_t)CC * HC / 2;                             // 16K ushort
  int* iws = (int*)(ws + off);
  size_t ioff = 0;
  int* hist = iws + ioff;     ioff += NN;
  int* ptr = iws + ioff;      ioff += NN + 1;
  int* cursor = iws + ioff;   ioff += NN;
  int* bsum = iws + ioff;     ioff += NB;
  int* boff = iws + ioff;     ioff += NB;

  hipMemsetAsync(hist, 0, NN * sizeof(int), stream);

  float* y_out = (float*)d_out;
  float* att_out = (float*)d_out + (size_t)NN * CC;

  k_prep<<<65, 256, 0, stream>>>(W, We, att_edge, Wbt, v_edge);
  k_hist<<<(EE / 4 + 255) / 256, 256, 0, stream>>>(ei, hist);
  k_xproj<<<NN / 16, 256, 0, stream>>>(node, Wbt, att_src, att_dst, x16, a_src,
                                       a_dst);
  k_scanA<<<NB, 256, 0, stream>>>(hist, bsum);
  k_scanB<<<1, 256, 0, stream>>>(bsum, boff, ptr);
  k_scanC<<<NB, 256, 0, stream>>>(hist, boff, ptr, cursor);
  k_edge_perm<<<(EE + 255) / 256, 256, 0, stream>>>(eatt, ei, a_src, a_dst,
                                                    v_edge, cursor, recs,
                                                    t_lin);
  k_gat<<<NN / 4, 256, 0, stream>>>(ptr, recs, x16, out_acc, rinv);
  k_att<<<(EE + 255) / 256, 256, 0, stream>>>(ei, t_lin, rinv, att_out);
  k_statsA<<<dim3(GG, SB), 256, 0, stream>>>(batch, out_acc, bias, p1, p2);
  k_statsB<<<GG, 64, 0, stream>>>(batch, p1, p2, gns, mean_s, istd);
  k_final<<<NN / 4, 256, 0, stream>>>(batch, out_acc, bias, mean_s, istd, gnw,
                                      gnb, y_out);
}